// Round 4
// baseline (136.940 us; speedup 1.0000x reference)
//
#include <hip/hip_runtime.h>

constexpr int T = 128;
constexpr int L = 9;
constexpr float LOG2E = 1.4426950408889634f;
constexpr float LN2   = 0.6931471805599453f;

__device__ __forceinline__ float fexp2(float x) {
    float r; asm("v_exp_f32 %0, %1" : "=v"(r) : "v"(x)); return r;
}
__device__ __forceinline__ float flog2(float x) {
    float r; asm("v_log_f32 %0, %1" : "=v"(r) : "v"(x)); return r;
}

__device__ __forceinline__ float getf(const float4 (&lv)[9], int idx) {
    const float4 q = lv[idx >> 2];
    const int c = idx & 3;
    return c == 0 ? q.x : c == 1 ? q.y : c == 2 ? q.z : q.w;
}

__device__ __forceinline__ void load_blk(float4 (&lv)[9], int4& labc,
                                         const float* gRow, const int* gLab, int bk)
{
    const float4* p = reinterpret_cast<const float4*>(gRow + bk * 36);
#pragma unroll
    for (int q = 0; q < 9; ++q) lv[q] = p[q];
    labc = *reinterpret_cast<const int4*>(gLab + bk * 4);
}

// one recurrence step (t >= 1)
__device__ __forceinline__ void step_t(bool upd, const float (&lg)[9], float usel, float bsel,
                                       float (&a)[9], float& unary, float& binary,
                                       const float (&et)[81])
{
    float el[9];
#pragma unroll
    for (int j = 0; j < 9; ++j) el[j] = fexp2(lg[j] * LOG2E);
    float s[9];
#pragma unroll
    for (int j = 0; j < 9; ++j) s[j] = a[0] * et[j];
#pragma unroll
    for (int i = 1; i < 9; ++i)
#pragma unroll
        for (int j = 0; j < 9; ++j)
            s[j] = fmaf(a[i], et[i * 9 + j], s[j]);
#pragma unroll
    for (int j = 0; j < 9; ++j) a[j] = upd ? s[j] * el[j] : a[j];
    unary  += upd ? usel : 0.0f;
    binary += upd ? bsel : 0.0f;
}

template <bool FIRSTBLK>
__device__ __forceinline__ void compute4(const float4 (&lv)[9], const int4& labc, int t0,
                                         float (&a)[9], float& unary, float& binary,
                                         int& E, int& plab, const float (&et)[81],
                                         const float* sTrans, int len, const float* gRow)
{
    const int labs[4] = {labc.x, labc.y, labc.z, labc.w};
#pragma unroll
    for (int tt = 0; tt < 4; ++tt) {
        const int t = t0 + tt;
        float lg[9];
#pragma unroll
        for (int j = 0; j < 9; ++j) lg[j] = getf(lv, tt * 9 + j);
        const int lab = labs[tt];
        const float usel = gRow[t * 9 + lab];        // L1 hit: same line as block load
        const float bsel = sTrans[plab * 9 + lab];   // LDS gather (81-entry table)
        const bool upd = t < len;
        if (FIRSTBLK && tt == 0) {
            // t = 0 init: alphas = logits[:,0,:]  (len >= 1 always)
#pragma unroll
            for (int j = 0; j < 9; ++j) a[j] = fexp2(lg[j] * LOG2E);
            unary = usel;
        } else {
            step_t(upd, lg, usel, bsel, a, unary, binary, et);
        }
        plab = lab;
    }
    // exponent rescale once per 4 steps (exact: a *= 2^-k, E += k)
    const unsigned ua = __float_as_uint(a[0]);
    const int k = (int)(ua >> 23) - 127;
    const float sc = __uint_as_float((254u - (ua >> 23)) << 23);
#pragma unroll
    for (int j = 0; j < 9; ++j) a[j] *= sc;
    E += k;
}

__launch_bounds__(64, 1)
__global__ void crf_kernel(const float* __restrict__ logits,
                           const int* __restrict__ labels,
                           const int* __restrict__ seq_lens,
                           const float* __restrict__ trans,
                           float* __restrict__ out)
{
    __shared__ float sTrans[81];
    const int lane = threadIdx.x;
    const int b = blockIdx.x * 64 + lane;

    for (int i = lane; i < 81; i += 64) sTrans[i] = trans[i];
    __syncthreads();

    // e^trans table, uniform across lanes, in VGPRs
    float et[81];
#pragma unroll
    for (int i = 0; i < 81; ++i) et[i] = fexp2(sTrans[i] * LOG2E);

    const int len = seq_lens[b];
    const float* gRow = logits + (long)b * (T * L);
    const int*   gLab = labels + (long)b * T;

    int maxlen = len;
#pragma unroll
    for (int off = 32; off > 0; off >>= 1)
        maxlen = max(maxlen, __shfl_xor(maxlen, off, 64));

    float a[9];
    float unary = 0.f, binary = 0.f;
    int E = 0, plab = 0;

    float4 bufA[9], bufB[9];
    int4 labA, labB;

    load_blk(bufA, labA, gRow, gLab, 0);
    load_blk(bufB, labB, gRow, gLab, 1);
    compute4<true>(bufA, labA, 0, a, unary, binary, E, plab, et, sTrans, len, gRow);

    // blocks 1..30 in pairs (15 iterations), block 31 peeled after
#pragma unroll 1
    for (int i = 1; i < 31; i += 2) {
        if (i * 4 >= maxlen) break;  // wave-uniform early exit
        load_blk(bufA, labA, gRow, gLab, i + 1);
        compute4<false>(bufB, labB, i * 4, a, unary, binary, E, plab, et, sTrans, len, gRow);
        load_blk(bufB, labB, gRow, gLab, i + 2);
        compute4<false>(bufA, labA, (i + 1) * 4, a, unary, binary, E, plab, et, sTrans, len, gRow);
    }
    if (124 < maxlen)
        compute4<false>(bufB, labB, 124, a, unary, binary, E, plab, et, sTrans, len, gRow);

    // log_norm = ln2 * (log2(sum a) + E); nll = log_norm - unary - binary
    float ssum = a[0];
#pragma unroll
    for (int j = 1; j < 9; ++j) ssum += a[j];
    float nll = LN2 * (flog2(ssum) + (float)E) - unary - binary;

#pragma unroll
    for (int off = 32; off > 0; off >>= 1) nll += __shfl_down(nll, off, 64);
    if (lane == 0) atomicAdd(out, nll);
}

extern "C" void kernel_launch(void* const* d_in, const int* in_sizes, int n_in,
                              void* d_out, int out_size, void* d_ws, size_t ws_size,
                              hipStream_t stream)
{
    const float* logits   = (const float*)d_in[0];
    const int*   labels   = (const int*)d_in[1];
    const int*   seq_lens = (const int*)d_in[2];
    const float* trans    = (const float*)d_in[3];
    float* out = (float*)d_out;

    const int B = in_sizes[2];           // 16384
    hipMemsetAsync(d_out, 0, sizeof(float), stream);
    crf_kernel<<<dim3(B / 64), dim3(64), 0, stream>>>(logits, labels, seq_lens, trans, out);
}